// Round 8
// baseline (205.225 us; speedup 1.0000x reference)
//
#include <hip/hip_runtime.h>
#include <stdint.h>
#include <stddef.h>

// BinarizeLinearWithFoldedBN on MI355X (gfx950).
// out[b,o] = dot(sign(x[b,:]), sign(w[o,:])) * scale[o] + bias[o]
//   scale = gamma/sqrt(var+eps), bias = beta - mean*scale (exact BN algebra)
// i8 (+1/-1) MFMA GEMM via mfma_i32_32x32x32_i8 (4404 TOPS), 256x256 tile,
// 8 waves, 4-buf slab rotation, register ping-pong pipelining (R6 skeleton),
// counted vmcnt, ONE barrier/slab. T1 XCD swizzle + T2 granule involution
// (measured 0 conflicts) + T5 setprio. Nontemporal C-stores keep packed
// operands L3-resident. Exact i32 dot.

#define BN_EPS 1e-5f
typedef int v4i  __attribute__((ext_vector_type(4)));
typedef int v16i __attribute__((ext_vector_type(16)));
typedef unsigned int v4u __attribute__((ext_vector_type(4)));

// ---------------- BN fold ----------------
__global__ void bn_prep_kernel(const float* __restrict__ g, const float* __restrict__ b,
                               const float* __restrict__ m, const float* __restrict__ v,
                               float* __restrict__ scale, float* __restrict__ bias, int n) {
  int i = blockIdx.x * blockDim.x + threadIdx.x;
  if (i >= n) return;
  float s = g[i] * rsqrtf(v[i] + BN_EPS);
  scale[i] = s;
  bias[i] = b[i] - m[i] * s;
}

// ---------------- pack f32 signs -> i8 +1/-1 (16 floats -> 16 bytes per thread) ----
// nontemporal input loads: f32 data is single-use, keep L3 for packed operands.
__global__ __launch_bounds__(256) void pack_sign_i8_kernel(
    const v4u* __restrict__ in, v4u* __restrict__ outp, int n16) {
  int t = blockIdx.x * blockDim.x + threadIdx.x;
  if (t >= n16) return;
  const v4u* p = in + (size_t)t * 4;
  uint32_t w[4];
#pragma unroll
  for (int i = 0; i < 4; ++i) {
    v4u u = __builtin_nontemporal_load(p + i);
    uint32_t m = (((uint32_t)((int)u.x >> 31)) & 0xFEu)
               | ((((uint32_t)((int)u.y >> 31)) & 0xFEu) << 8)
               | ((((uint32_t)((int)u.z >> 31)) & 0xFEu) << 16)
               | ((((uint32_t)((int)u.w >> 31)) & 0xFEu) << 24);
    w[i] = 0x01010101u ^ m;
  }
  v4u o; o.x = w[0]; o.y = w[1]; o.z = w[2]; o.w = w[3];
  outp[t] = o;
}

// ---------------- i8 MFMA GEMM ----------------
// LDS (128 KiB): A slab buf q (q=0..3): q*16384 (256 rows x 64 B)
//                B slab buf q:          65536 + q*16384
// T2 16B-granule involution: LDS(row R, chunk C) = global granule C ^ ((R>>1)&3);
//   write: linear gload_lds dest + pre-swizzled SOURCE granule (R4/R6: 0 conflicts);
//   read (32x32 frags): row = base + (lane&31), granule = (ks*2+(lane>>5)) ^ ((lane>>1)&3).

#define BAR() asm volatile("s_barrier" ::: "memory")
#define WAITV8() asm volatile("s_waitcnt vmcnt(8)" ::: "memory")
#define WAITV4() asm volatile("s_waitcnt vmcnt(4)" ::: "memory")
#define WAITV0() asm volatile("s_waitcnt vmcnt(0)" ::: "memory")
#define LGKM0() asm volatile("s_waitcnt lgkmcnt(0)" ::: "memory")
#define SCHED0() __builtin_amdgcn_sched_barrier(0)

__global__ __launch_bounds__(512, 2) void bgemm_i8_32(
    const int8_t* __restrict__ A8, const int8_t* __restrict__ B8,
    const float* __restrict__ scale, const float* __restrict__ bias,
    float* __restrict__ out, int M, int N, int K) {
  __shared__ __align__(16) int8_t lds[131072];

  const int tid = threadIdx.x;
  const int lane = tid & 63;
  const int wid = tid >> 6;      // 0..7
  const int wm = wid >> 2;       // 0..1  (128-row band)
  const int wn = wid & 3;        // 0..3  (64-col band)

  // T1: bijective XCD swizzle (nwg % 8 == 0 here: 32*16 = 512)
  const int nbx = N >> 8;
  const int nwg = (M >> 8) * nbx;
  const int cpx = nwg >> 3;
  const int bid = (int)blockIdx.x;
  const int swz = (bid & 7) * cpx + (bid >> 3);
  const int row0 = (swz / nbx) << 8;
  const int col0 = (swz % nbx) << 8;

  const int rl = lane & 31;                 // row/col within 32-tile
  const int hi = lane >> 5;                 // k-half selector
  const int key = (lane >> 1) & 3;          // T2 read key ((row>>1)&3 == (lane>>1)&3)
  const int g0 = ((hi) ^ key) << 4;         // ks=0 granule byte offset
  const int g1 = ((2 | hi) ^ key) << 4;     // ks=1
  const int aoff = (wm * 128 + rl) * 64;    // + mt*2048 + g{ks}
  const int boff = (wn * 64 + rl) * 64;     // + nt*2048 + g{ks}

  const int srow = wid * 16 + (lane >> 2);  // staging row (2nd inst adds 128)
  const int sch = (((lane & 3) ^ ((lane >> 3) & 3)) << 4);  // pre-swizzled source granule
  const int ldw = wid << 10;                // wave slot in 8KB half-slab

  const size_t rstr = (size_t)128 * K;
  const int8_t* aSt = A8 + (size_t)(row0 + srow) * K + sch;
  const int8_t* bSt = B8 + (size_t)(col0 + srow) * K + sch;

  v16i acc[4][2];
#pragma unroll
  for (int i = 0; i < 4; ++i)
#pragma unroll
    for (int n = 0; n < 2; ++n)
#pragma unroll
      for (int e = 0; e < 16; ++e) acc[i][n][e] = 0;

  v4i A[2][8];   // [set][ks*4 + mt]
  v4i Bf[2][4];  // [set][ks*2 + nt]

#define STAGE(s) do {                                                                 \
  const int bb_ = ((s) & 3) * 16384;                                                  \
  __builtin_amdgcn_global_load_lds(                                                   \
      (const __attribute__((address_space(1))) uint32_t*)(aSt + (size_t)(s) * 64),    \
      (__attribute__((address_space(3))) uint32_t*)(lds + bb_ + ldw), 16, 0, 0);      \
  __builtin_amdgcn_global_load_lds(                                                   \
      (const __attribute__((address_space(1))) uint32_t*)(aSt + rstr + (size_t)(s) * 64), \
      (__attribute__((address_space(3))) uint32_t*)(lds + bb_ + 8192 + ldw), 16, 0, 0); \
  __builtin_amdgcn_global_load_lds(                                                   \
      (const __attribute__((address_space(1))) uint32_t*)(bSt + (size_t)(s) * 64),    \
      (__attribute__((address_space(3))) uint32_t*)(lds + 65536 + bb_ + ldw), 16, 0, 0); \
  __builtin_amdgcn_global_load_lds(                                                   \
      (const __attribute__((address_space(1))) uint32_t*)(bSt + rstr + (size_t)(s) * 64), \
      (__attribute__((address_space(3))) uint32_t*)(lds + 65536 + bb_ + 8192 + ldw), 16, 0, 0); \
} while (0)

// A fragments for one k-step: 4 tiles (mt 0..3), granule offset gk, into A[cs][idx0..idx0+3]
#define RD_A_KS(cs, gk, idx0, q) do {                                                 \
  const int8_t* p_ = lds + (q) * 16384 + aoff + (gk);                                 \
  A[cs][(idx0) + 0] = *(const v4i*)(p_);                                              \
  A[cs][(idx0) + 1] = *(const v4i*)(p_ + 2048);                                       \
  A[cs][(idx0) + 2] = *(const v4i*)(p_ + 4096);                                       \
  A[cs][(idx0) + 3] = *(const v4i*)(p_ + 6144);                                       \
} while (0)

// B fragments for BOTH k-steps: (nt 0..1) x (ks 0..1)
#define RD_B_BOTH(cs, q) do {                                                         \
  const int8_t* p_ = lds + 65536 + (q) * 16384 + boff;                                \
  Bf[cs][0] = *(const v4i*)(p_ + g0);                                                 \
  Bf[cs][1] = *(const v4i*)(p_ + g0 + 2048);                                          \
  Bf[cs][2] = *(const v4i*)(p_ + g1);                                                 \
  Bf[cs][3] = *(const v4i*)(p_ + g1 + 2048);                                          \
} while (0)

#define MFMA8(ks, cs) do {                                                            \
  __builtin_amdgcn_s_setprio(1);                                                      \
  _Pragma("unroll")                                                                   \
  for (int nt_ = 0; nt_ < 2; ++nt_)                                                   \
    _Pragma("unroll")                                                                 \
    for (int mt_ = 0; mt_ < 4; ++mt_)                                                 \
      acc[mt_][nt_] = __builtin_amdgcn_mfma_i32_32x32x32_i8(                          \
          A[cs][(ks) * 4 + mt_], Bf[cs][(ks) * 2 + nt_], acc[mt_][nt_], 0, 0, 0);     \
  __builtin_amdgcn_s_setprio(0);                                                      \
} while (0)

// one 64B slab: ks1-reads issue under ks0-MFMAs; next-slab B+A-ks0 reads issue
// under ks1-MFMAs; ONE barrier per slab; LGKM0 before BAR closes the
// read-vs-overwrite window for buf t&3 (stage(t+4) targets it after next BAR).
#define SLAB_BODY(t, cs, ns, STG, WV) do {                                            \
  STG;                                                                                \
  RD_A_KS(cs, g1, 4, (t) & 3);                                                        \
  SCHED0();                                                                           \
  MFMA8(0, cs);                                                                       \
  LGKM0();                                                                            \
  WV;                                                                                 \
  BAR();                                                                              \
  RD_B_BOTH(ns, (t + 1) & 3);                                                         \
  RD_A_KS(ns, g0, 0, (t + 1) & 3);                                                    \
  SCHED0();                                                                           \
  MFMA8(1, cs);                                                                       \
} while (0)

#define SLAB_LAST(t, cs) do {                                                         \
  RD_A_KS(cs, g1, 4, (t) & 3);                                                        \
  SCHED0();                                                                           \
  MFMA8(0, cs);                                                                       \
  MFMA8(1, cs);                                                                       \
} while (0)

  const int NT = K >> 6;   // 64-byte K-slabs; even, >= 8 (K = 4096 -> 64)

  // ---- prologue: prefetch slabs 0,1,2; certify slab 0; preload its B + A-ks0 frags
  STAGE(0); STAGE(1); STAGE(2);
  WAITV8();           // own slab-0 staging loads retired (12 -> 8 outstanding)
  BAR();              // all waves -> slab 0 fully in LDS
  RD_B_BOTH(0, 0);
  RD_A_KS(0, g0, 0, 0);

  // ---- main loop: slab t uses set t&1; stage slab t+3
  int t = 0;
  for (; t + 1 < NT - 3; t += 2) {
    SLAB_BODY(t,     0, 1, STAGE(t + 3), WAITV8());
    SLAB_BODY(t + 1, 1, 0, STAGE(t + 4), WAITV8());
  }
  // NT even -> exactly one leftover fully-staged slab (t == NT-4, set 0)
  SLAB_BODY(NT - 4, 0, 1, STAGE(NT - 1), WAITV8());
  // tail: no staging; drain 8 -> 4 -> 0
  SLAB_BODY(NT - 3, 1, 0, (void)0, WAITV4());
  SLAB_BODY(NT - 2, 0, 1, (void)0, WAITV0());
  SLAB_LAST(NT - 1, 1);

  // ---- epilogue: 32x32 C/D layout: col = lane&31, row = (reg&3) + 8*(reg>>2) + 4*(lane>>5)
  // nontemporal stores: output is write-once, keep packed operands resident in L3.
  const int cb = col0 + wn * 64 + rl;
  float scv[2], biv[2];
#pragma unroll
  for (int n = 0; n < 2; ++n) {
    scv[n] = scale[cb + n * 32];
    biv[n] = bias[cb + n * 32];
  }
#pragma unroll
  for (int mt = 0; mt < 4; ++mt) {
    const int rb = row0 + wm * 128 + mt * 32 + 4 * hi;
#pragma unroll
    for (int nt = 0; nt < 2; ++nt) {
      const int c = cb + nt * 32;
#pragma unroll
      for (int reg = 0; reg < 16; ++reg) {
        const int r = rb + (reg & 3) + 8 * (reg >> 2);
        __builtin_nontemporal_store(
            fmaf((float)acc[mt][nt][reg], scv[nt], biv[nt]),
            out + (size_t)r * N + c);
      }
    }
  }

#undef STAGE
#undef RD_A_KS
#undef RD_B_BOTH
#undef MFMA8
#undef SLAB_BODY
#undef SLAB_LAST
}

// ======================= launch =======================
extern "C" void kernel_launch(void* const* d_in, const int* in_sizes, int n_in,
                              void* d_out, int out_size, void* d_ws, size_t ws_size,
                              hipStream_t stream) {
  const float* x = (const float*)d_in[0];
  const float* w = (const float*)d_in[1];
  const float* gamma = (const float*)d_in[2];
  const float* beta = (const float*)d_in[3];
  const float* mean = (const float*)d_in[4];
  const float* var = (const float*)d_in[5];
  float* out = (float*)d_out;

  const int OUT = in_sizes[2];            // 4096
  const int IN = in_sizes[1] / OUT;       // 4096
  const int B = in_sizes[0] / IN;         // 8192

  int8_t* a8 = (int8_t*)d_ws;
  int8_t* b8 = a8 + (size_t)B * IN;
  float* scale = (float*)(b8 + (size_t)OUT * IN);
  float* bias = scale + OUT;

  const int n16x = B * (IN / 16);
  const int n16w = OUT * (IN / 16);
  pack_sign_i8_kernel<<<(n16x + 255) / 256, 256, 0, stream>>>(
      (const v4u*)x, (v4u*)a8, n16x);
  pack_sign_i8_kernel<<<(n16w + 255) / 256, 256, 0, stream>>>(
      (const v4u*)w, (v4u*)b8, n16w);
  bn_prep_kernel<<<(OUT + 255) / 256, 256, 0, stream>>>(
      gamma, beta, mean, var, scale, bias, OUT);

  dim3 grid((B >> 8) * (OUT >> 8));
  bgemm_i8_32<<<grid, 512, 0, stream>>>(a8, b8, scale, bias, out, B, OUT, IN);
}

// Round 10
// 130.286 us; speedup vs baseline: 1.5752x; 1.5752x over previous
//
#include <hip/hip_runtime.h>
#include <stdint.h>
#include <stddef.h>

// BinarizeLinearWithFoldedBN on MI355X (gfx950).
// out[b,o] = dot(sign(x[b,:]), sign(w[o,:])) * scale[o] + bias[o]
//   scale = gamma/sqrt(var+eps), bias = beta - mean*scale (exact BN algebra)
// FP4 (+1/-1 in e2m1) MFMA GEMM via v_mfma_f32_32x32x64_f8f6f4 cbsz:4 blgp:4
// (inline asm, non-scaled; fp4 A/B = 4-dword tuples). 256x256 tile, 8 waves,
// 4-buf 64B-slab rotation (one slab = K=128 in fp4), prefetch distance 3,
// counted vmcnt, 1 barrier/slab. T1 XCD swizzle + T2 granule involution +
// T5 setprio. f32 accumulation of +/-1 products is exact.

#define BN_EPS 1e-5f
typedef int   v4i  __attribute__((ext_vector_type(4)));
typedef float v16f __attribute__((ext_vector_type(16)));
typedef unsigned int u32;

// ---------------- BN fold ----------------
__global__ void bn_prep_kernel(const float* __restrict__ g, const float* __restrict__ b,
                               const float* __restrict__ m, const float* __restrict__ v,
                               float* __restrict__ scale, float* __restrict__ bias, int n) {
  int i = blockIdx.x * blockDim.x + threadIdx.x;
  if (i >= n) return;
  float s = g[i] * rsqrtf(v[i] + BN_EPS);
  scale[i] = s;
  bias[i] = b[i] - m[i] * s;
}

// ---------------- pack f32 signs -> fp4 e2m1 +/-1 nibbles ----------------
// +1 -> 0x2 (s0 e01 m0), -1 -> 0xA. 32 floats (8 uint4) -> 16 nibble-packed bytes.
// nibble j of dword = element 8*word + j (little-endian k-order; A and B share it).
__global__ __launch_bounds__(256) void pack_sign_fp4_kernel(
    const uint4* __restrict__ in, uint4* __restrict__ outp, int n32) {
  int t = blockIdx.x * blockDim.x + threadIdx.x;
  if (t >= n32) return;
  const uint4* p = in + (size_t)t * 8;
  u32 w[4];
#pragma unroll
  for (int j = 0; j < 4; ++j) {
    uint4 u0 = p[2 * j];
    uint4 u1 = p[2 * j + 1];
    u32 h0 = 0x2222u | ((u0.x >> 28) & 0x8u) | (((u0.y >> 28) & 0x8u) << 4)
                     | (((u0.z >> 28) & 0x8u) << 8) | (((u0.w >> 28) & 0x8u) << 12);
    u32 h1 = 0x2222u | ((u1.x >> 28) & 0x8u) | (((u1.y >> 28) & 0x8u) << 4)
                     | (((u1.z >> 28) & 0x8u) << 8) | (((u1.w >> 28) & 0x8u) << 12);
    w[j] = h0 | (h1 << 16);
  }
  uint4 o; o.x = w[0]; o.y = w[1]; o.z = w[2]; o.w = w[3];
  outp[t] = o;
}

// ---------------- fp4 MFMA GEMM ----------------
// Row bytes RB = IN/2. LDS (128 KiB): A slab buf q: q*16384 (256 rows x 64 B);
// B slab buf q: 65536 + q*16384. One slab = 64 B/row = K=128 = 2 MFMA k-steps.
// T2 granule involution (R4/R6-verified): LDS(row R, chunk C) = granule C ^ ((R>>1)&3);
//   write: linear gload_lds dest + pre-swizzled SOURCE granule;
//   read: granule (ks*2 + (lane>>5)) ^ ((lane>>1)&3).

#define BAR() asm volatile("s_barrier" ::: "memory")
#define WAITV8() asm volatile("s_waitcnt vmcnt(8)" ::: "memory")
#define WAITV4() asm volatile("s_waitcnt vmcnt(4)" ::: "memory")
#define WAITV0() asm volatile("s_waitcnt vmcnt(0)" ::: "memory")
#define LGKM0() asm volatile("s_waitcnt lgkmcnt(0)" ::: "memory")

// fp4 (cbsz:4 / blgp:4): A and B are 4-dword register tuples
#define MFMA4(accv, av, bv) \
  asm("v_mfma_f32_32x32x64_f8f6f4 %0, %1, %2, %0 cbsz:4 blgp:4" \
      : "+v"(accv) : "v"(av), "v"(bv))

__global__ __launch_bounds__(512, 2) void bgemm_fp4(
    const int8_t* __restrict__ A4, const int8_t* __restrict__ B4,
    const float* __restrict__ scale, const float* __restrict__ bias,
    float* __restrict__ out, int M, int N, int RB /* = IN/2 bytes per row */) {
  __shared__ __align__(16) int8_t lds[131072];

  const int tid = threadIdx.x;
  const int lane = tid & 63;
  const int wid = tid >> 6;      // 0..7
  const int wm = wid >> 2;       // 0..1  (128-row band)
  const int wn = wid & 3;        // 0..3  (64-col band)

  // T1: bijective XCD swizzle (nwg % 8 == 0 here: 32*16 = 512)
  const int nbx = N >> 8;
  const int nwg = (M >> 8) * nbx;
  const int cpx = nwg >> 3;
  const int bid = (int)blockIdx.x;
  const int swz = (bid & 7) * cpx + (bid >> 3);
  const int row0 = (swz / nbx) << 8;
  const int col0 = (swz % nbx) << 8;

  const int rl = lane & 31;                 // row/col within 32-tile
  const int hi = lane >> 5;                 // k-half selector within a k-step
  const int key = (lane >> 1) & 3;          // (row>>1)&3 == (rl>>1)&3
  const int g0 = ((hi) ^ key) << 4;         // ks=0 granule byte offset
  const int g1 = ((2 | hi) ^ key) << 4;     // ks=1
  const int aoff = (wm * 128 + rl) * 64;    // + mt*2048 + g{ks}
  const int boff = (wn * 64 + rl) * 64;     // + nt*2048 + g{ks}

  const int srow = wid * 16 + (lane >> 2);  // staging row (2nd inst adds 128)
  const int sch = (((lane & 3) ^ ((lane >> 3) & 3)) << 4);  // pre-swizzled source granule
  const int ldw = wid << 10;                // wave slot in 8KB half-slab

  const size_t rstr = (size_t)128 * RB;
  const int8_t* aSt = A4 + (size_t)(row0 + srow) * RB + sch;
  const int8_t* bSt = B4 + (size_t)(col0 + srow) * RB + sch;

  v16f acc[4][2];
#pragma unroll
  for (int i = 0; i < 4; ++i)
#pragma unroll
    for (int n = 0; n < 2; ++n)
#pragma unroll
      for (int e = 0; e < 16; ++e) acc[i][n][e] = 0.0f;

#define STAGE(s) do {                                                                 \
  const int bb_ = ((s) & 3) * 16384;                                                  \
  __builtin_amdgcn_global_load_lds(                                                   \
      (const __attribute__((address_space(1))) uint32_t*)(aSt + (size_t)(s) * 64),    \
      (__attribute__((address_space(3))) uint32_t*)(lds + bb_ + ldw), 16, 0, 0);      \
  __builtin_amdgcn_global_load_lds(                                                   \
      (const __attribute__((address_space(1))) uint32_t*)(aSt + rstr + (size_t)(s) * 64), \
      (__attribute__((address_space(3))) uint32_t*)(lds + bb_ + 8192 + ldw), 16, 0, 0); \
  __builtin_amdgcn_global_load_lds(                                                   \
      (const __attribute__((address_space(1))) uint32_t*)(bSt + (size_t)(s) * 64),    \
      (__attribute__((address_space(3))) uint32_t*)(lds + 65536 + bb_ + ldw), 16, 0, 0); \
  __builtin_amdgcn_global_load_lds(                                                   \
      (const __attribute__((address_space(1))) uint32_t*)(bSt + rstr + (size_t)(s) * 64), \
      (__attribute__((address_space(3))) uint32_t*)(lds + 65536 + bb_ + 8192 + ldw), 16, 0, 0); \
} while (0)

// one K=128 slab from buf q: 4 B-frag reads (live across), then per mt:
// 2 A-frag reads + 4 MFMAs. Register deps give the compiler counted lgkmcnt.
#define COMPUTE(q) do {                                                               \
  const int8_t* bp_ = lds + 65536 + (q) * 16384 + boff;                               \
  v4i B00 = *(const v4i*)(bp_ + g0);       v4i B01 = *(const v4i*)(bp_ + 2048 + g0);  \
  v4i B10 = *(const v4i*)(bp_ + g1);       v4i B11 = *(const v4i*)(bp_ + 2048 + g1);  \
  __builtin_amdgcn_s_setprio(1);                                                      \
  _Pragma("unroll")                                                                   \
  for (int mt_ = 0; mt_ < 4; ++mt_) {                                                 \
    const int8_t* ap_ = lds + (q) * 16384 + aoff + mt_ * 2048;                        \
    v4i A0 = *(const v4i*)(ap_ + g0);                                                 \
    v4i A1 = *(const v4i*)(ap_ + g1);                                                 \
    MFMA4(acc[mt_][0], A0, B00);                                                      \
    MFMA4(acc[mt_][1], A0, B01);                                                      \
    MFMA4(acc[mt_][0], A1, B10);                                                      \
    MFMA4(acc[mt_][1], A1, B11);                                                      \
  }                                                                                   \
  __builtin_amdgcn_s_setprio(0);                                                      \
} while (0)

  const int NT = RB >> 6;   // 64-byte slabs (K=128 each); 32 for IN=4096

  // ---- prologue: prefetch slabs 0,1,2; certify slab 0
  STAGE(0); STAGE(1); STAGE(2);
  WAITV8();           // own slab-0 staging loads retired
  BAR();              // all waves -> slab 0 fully in LDS

  // ---- main loop: compute slab t, stage slab t+3 (into buf (t+3)&3 = (t-1)&3,
  // whose readers drained at the previous LGKM0+BAR)
  for (int t = 0; t < NT - 3; ++t) {
    STAGE(t + 3);
    COMPUTE(t & 3);
    LGKM0();          // this slab's reads drained (ran under the MFMAs)
    WAITV8();         // slab t+1's 4 loads retired (12 outstanding -> 8)
    BAR();            // all waves: slab t+1 ready; buf t&3 reusable next stage
  }
  // tail: no staging; drain 8 -> 4 -> 0
  COMPUTE((NT - 3) & 3); LGKM0(); WAITV4(); BAR();
  COMPUTE((NT - 2) & 3); LGKM0(); WAITV0(); BAR();
  COMPUTE((NT - 1) & 3);
  asm volatile("s_nop 7\n\ts_nop 7" :::);   // MFMA write -> VALU read hazard guard

  // ---- epilogue: 32x32 C/D layout: col = lane&31, row = (reg&3) + 8*(reg>>2) + 4*(lane>>5)
  const int cb = col0 + wn * 64 + rl;
  float scv[2], biv[2];
#pragma unroll
  for (int n = 0; n < 2; ++n) {
    scv[n] = scale[cb + n * 32];
    biv[n] = bias[cb + n * 32];
  }
#pragma unroll
  for (int mt = 0; mt < 4; ++mt) {
    const int rb = row0 + wm * 128 + mt * 32 + 4 * hi;
#pragma unroll
    for (int nt = 0; nt < 2; ++nt) {
      const int c = cb + nt * 32;
#pragma unroll
      for (int reg = 0; reg < 16; ++reg) {
        const int r = rb + (reg & 3) + 8 * (reg >> 2);
        out[(size_t)r * N + c] = fmaf(acc[mt][nt][reg], scv[nt], biv[nt]);
      }
    }
  }

#undef STAGE
#undef COMPUTE
}

// ======================= launch =======================
extern "C" void kernel_launch(void* const* d_in, const int* in_sizes, int n_in,
                              void* d_out, int out_size, void* d_ws, size_t ws_size,
                              hipStream_t stream) {
  const float* x = (const float*)d_in[0];
  const float* w = (const float*)d_in[1];
  const float* gamma = (const float*)d_in[2];
  const float* beta = (const float*)d_in[3];
  const float* mean = (const float*)d_in[4];
  const float* var = (const float*)d_in[5];
  float* out = (float*)d_out;

  const int OUT = in_sizes[2];            // 4096
  const int IN = in_sizes[1] / OUT;       // 4096
  const int B = in_sizes[0] / IN;         // 8192
  const int RB = IN / 2;                  // packed fp4 bytes per row

  int8_t* a4 = (int8_t*)d_ws;
  int8_t* b4 = a4 + (size_t)B * RB;
  float* scale = (float*)(b4 + (size_t)OUT * RB);
  float* bias = scale + OUT;

  const int n32x = B * (IN / 32);
  const int n32w = OUT * (IN / 32);
  pack_sign_fp4_kernel<<<(n32x + 255) / 256, 256, 0, stream>>>(
      (const uint4*)x, (uint4*)a4, n32x);
  pack_sign_fp4_kernel<<<(n32w + 255) / 256, 256, 0, stream>>>(
      (const uint4*)w, (uint4*)b4, n32w);
  bn_prep_kernel<<<(OUT + 255) / 256, 256, 0, stream>>>(
      gamma, beta, mean, var, scale, bias, OUT);

  dim3 grid((B >> 8) * (OUT >> 8));
  bgemm_fp4<<<grid, 512, 0, stream>>>(a4, b4, scale, bias, out, B, OUT, RB);
}